// Round 16
// baseline (312.334 us; speedup 1.0000x reference)
//
#include <hip/hip_runtime.h>
#include <hip/hip_fp16.h>

// HGNN aggregation: out = x + segment_sum(x[src_idx], dst_idx)
// x: [100000, 128] f32; src_idx/dst_idx: [2,000,000] int32.
//
// Round 16: r15 (sliced L2-resident gather + register accum) with the
// non-temporal hints r14 proved necessary: arena / x-residual / out are
// nt (no L2 allocation -> slice stays resident); slice loads cached.
// Gather: 4 lanes/node x 4 dims, 16 nodes/wave, 4-deep chains with
// zero-row predication.

constexpr int DIM = 128;
constexpr int BSHIFT = 7;            // 128 nodes per bucket
constexpr int GNODES = 1 << BSHIFT;  // 128
constexpr int MAXB = 1024;           // max buckets (N <= 131072)
constexpr int CE = 8192;             // edges per partition chunk
constexpr int CAP_MAX = 3072;        // arena slots per bucket (mean 2558)

typedef float v4f __attribute__((ext_vector_type(4)));

__global__ void hgnn_fused_prep(const float4* __restrict__ x4,
                                ushort4* __restrict__ xh4, int nnodes,
                                const int* __restrict__ src,
                                const int* __restrict__ dst,
                                int* __restrict__ cursor,
                                int* __restrict__ arena, int cap,
                                int* __restrict__ spillCnt,
                                int2* __restrict__ spill, int spillCap,
                                int nedges, int nbk, int nPart) {
    __shared__ int h[MAXB];
    __shared__ int lb[MAXB];
    const int tid = threadIdx.x;

    if ((int)blockIdx.x < nPart) {
        // ---- partition path ----
        int c0 = blockIdx.x * CE;
        int c1 = min(c0 + CE, nedges);
        for (int i = tid; i < nbk; i += blockDim.x) h[i] = 0;
        __syncthreads();
        for (int i = c0 + tid; i < c1; i += blockDim.x)
            atomicAdd(&h[dst[i] >> BSHIFT], 1);
        __syncthreads();
        for (int i = tid; i < nbk; i += blockDim.x)
            lb[i] = h[i] ? atomicAdd(&cursor[i], h[i]) : 0;
        __syncthreads();
        for (int i = c0 + tid; i < c1; i += blockDim.x) {
            int s = src[i];
            int d = dst[i];
            int bk = d >> BSHIFT;
            int pos = atomicAdd(&lb[bk], 1);
            if (pos < cap) {
                arena[(size_t)bk * cap + pos] = s | ((d & (GNODES - 1)) << 17);
            } else {
                int sp = atomicAdd(spillCnt, 1);
                if (sp < spillCap) spill[sp] = make_int2(s, d);
            }
        }
    } else {
        // ---- convert path: x -> 8 contiguous f16 slices, + zero row N ----
        int bid = blockIdx.x - nPart;
        int nconv = gridDim.x - nPart;
        int i = bid * blockDim.x + tid;
        int stride = nconv * blockDim.x;
        int total = (nnodes + 1) * 8;
        int rowsPerSlice = nnodes + 1;
        for (int k = i; k < total; k += stride) {
            int node = k >> 3;
            int g = k & 7;
            ushort4* wp = xh4 + (size_t)g * rowsPerSlice * 4 + (size_t)node * 4;
            if (node == nnodes) {
                ushort4 z; z.x = 0; z.y = 0; z.z = 0; z.w = 0;
#pragma unroll
                for (int t = 0; t < 4; ++t) wp[t] = z;
            } else {
                size_t rbase = (size_t)node * 32 + g * 4;
#pragma unroll
                for (int t = 0; t < 4; ++t) {
                    float4 v = x4[rbase + t];
                    ushort4 o;
                    o.x = __half_as_ushort(__float2half_rn(v.x));
                    o.y = __half_as_ushort(__float2half_rn(v.y));
                    o.z = __half_as_ushort(__float2half_rn(v.z));
                    o.w = __half_as_ushort(__float2half_rn(v.w));
                    wp[t] = o;
                }
            }
        }
    }
}

// one block per bucket: LDS counting sort by local node id.
__global__ void hgnn_refine(int* __restrict__ arena, int cap,
                            const int* __restrict__ cursor,
                            int* __restrict__ offsets, int nnodes) {
    __shared__ int ebuf[CAP_MAX];
    __shared__ int hoff[GNODES + 1];
    __shared__ int cur[GNODES];
    const int b = blockIdx.x;
    const int tid = threadIdx.x;

    int cnt = cursor[b];
    if (cnt > cap) cnt = cap;
    int* ar = arena + (size_t)b * cap;

    for (int i = tid; i < GNODES; i += blockDim.x) cur[i] = 0;
    __syncthreads();
    for (int i = tid; i < cnt; i += blockDim.x) {
        int p = ar[i];
        ebuf[i] = p;
        atomicAdd(&cur[p >> 17], 1);
    }
    __syncthreads();

    int myc = (tid < GNODES) ? cur[tid] : 0;
    if (tid < GNODES) hoff[tid + 1] = myc;
    if (tid == 0) hoff[0] = 0;
    __syncthreads();
    for (int off = 1; off < GNODES; off <<= 1) {
        int v = (tid < GNODES && tid >= off) ? hoff[tid + 1 - off] : 0;
        __syncthreads();
        if (tid < GNODES) hoff[tid + 1] += v;
        __syncthreads();
    }
    if (tid < GNODES) cur[tid] = hoff[tid];
    __syncthreads();

    if (tid < GNODES) {
        int node = (b << BSHIFT) + tid;
        if (node < nnodes) offsets[node] = hoff[tid];
    }
    for (int i = tid; i < cnt; i += blockDim.x) {
        int p = ebuf[i];
        int pos = atomicAdd(&cur[p >> 17], 1);
        ar[pos] = p & 0x1FFFF;    // bare src id
    }
}

// block = (bucket b, dimgroup g=blockIdx&7). 4 lanes/node x 4 dims,
// 16 nodes/wave, 4-deep register f16 chains, nt streaming traffic.
__global__ void hgnn_aggregate_dsplit(const float* __restrict__ x,
                                      const uint2* __restrict__ xhT,
                                      const int* __restrict__ arena, int cap,
                                      const int* __restrict__ cursor,
                                      const int* __restrict__ offsets,
                                      float* __restrict__ out, int nnodes) {
    const int b = blockIdx.x >> 3;
    const int g = blockIdx.x & 7;      // XCD round-robin alignment
    const int tid = threadIdx.x;
    const int sub = tid & 3;
    const int ZROW = nnodes;           // zeroed pad row per slice

    int cnt = cursor[b];
    if (cnt > cap) cnt = cap;
    const int* ar = arena + (size_t)b * cap;
    const uint2* slice = xhT + (size_t)g * (nnodes + 1) * 4;  // 4 uint2/row

    for (int pass = 0; pass < 2; ++pass) {
        int nr = pass * 64 + (tid >> 2);      // local node 0..127
        int node = (b << BSHIFT) + nr;
        if (node >= nnodes) break;

        int s0 = offsets[node];
        int e0 = (nr == GNODES - 1 || node + 1 >= nnodes) ? cnt
                                                          : offsets[node + 1];
        int m = e0 - s0;

        const __half2 hz = __floats2half2_rn(0.f, 0.f);
        __half2 c0lo = hz, c0hi = hz, c1lo = hz, c1hi = hz;
        __half2 c2lo = hz, c2hi = hz, c3lo = hz, c3hi = hz;

        for (int j = 0; j < m; j += 4) {
            int p0 = (j + 0 < m) ? __builtin_nontemporal_load(ar + s0 + j + 0) : ZROW;
            int p1 = (j + 1 < m) ? __builtin_nontemporal_load(ar + s0 + j + 1) : ZROW;
            int p2 = (j + 2 < m) ? __builtin_nontemporal_load(ar + s0 + j + 2) : ZROW;
            int p3 = (j + 3 < m) ? __builtin_nontemporal_load(ar + s0 + j + 3) : ZROW;
            uint2 v0 = slice[(size_t)p0 * 4 + sub];
            uint2 v1 = slice[(size_t)p1 * 4 + sub];
            uint2 v2 = slice[(size_t)p2 * 4 + sub];
            uint2 v3 = slice[(size_t)p3 * 4 + sub];
            c0lo = __hadd2(c0lo, *reinterpret_cast<const __half2*>(&v0.x));
            c0hi = __hadd2(c0hi, *reinterpret_cast<const __half2*>(&v0.y));
            c1lo = __hadd2(c1lo, *reinterpret_cast<const __half2*>(&v1.x));
            c1hi = __hadd2(c1hi, *reinterpret_cast<const __half2*>(&v1.y));
            c2lo = __hadd2(c2lo, *reinterpret_cast<const __half2*>(&v2.x));
            c2hi = __hadd2(c2hi, *reinterpret_cast<const __half2*>(&v2.y));
            c3lo = __hadd2(c3lo, *reinterpret_cast<const __half2*>(&v3.x));
            c3hi = __hadd2(c3hi, *reinterpret_cast<const __half2*>(&v3.y));
        }

        __half2 slo = __hadd2(__hadd2(c0lo, c1lo), __hadd2(c2lo, c3lo));
        __half2 shi = __hadd2(__hadd2(c0hi, c1hi), __hadd2(c2hi, c3hi));
        float2 flo = __half22float2(slo);
        float2 fhi = __half22float2(shi);

        // out float4 slot: node*32 + g*4 + sub (4 lanes = one 64B line)
        size_t o = (size_t)node * 32 + g * 4 + sub;
        v4f xv = __builtin_nontemporal_load((const v4f*)x + o);
        v4f rv = {xv.x + flo.x, xv.y + flo.y, xv.z + fhi.x, xv.w + fhi.y};
        __builtin_nontemporal_store(rv, (v4f*)out + o);
    }
}

// handles arena-overflow edges (expected none on this data); exact f32 path
__global__ void hgnn_spill_apply(const float4* __restrict__ x4,
                                 const int* __restrict__ spillCnt,
                                 const int2* __restrict__ spill,
                                 float* __restrict__ out, int spillCap) {
    int n = *spillCnt;
    if (n > spillCap) n = spillCap;
    int i = blockIdx.x * blockDim.x + threadIdx.x;
    int stride = gridDim.x * blockDim.x;
    for (int k = i; k < n * 32; k += stride) {
        int e = k >> 5;
        int cc = k & 31;
        int2 sd = spill[e];
        float4 v = x4[(size_t)sd.x * 32 + cc];
        float* o = out + (size_t)sd.y * DIM + cc * 4;
        atomicAdd(o + 0, v.x);
        atomicAdd(o + 1, v.y);
        atomicAdd(o + 2, v.z);
        atomicAdd(o + 3, v.w);
    }
}

static inline size_t align256(size_t v) { return (v + 255) & ~(size_t)255; }

extern "C" void kernel_launch(void* const* d_in, const int* in_sizes, int n_in,
                              void* d_out, int out_size, void* d_ws, size_t ws_size,
                              hipStream_t stream) {
    const float* x = (const float*)d_in[0];
    const int* src = (const int*)d_in[1];
    const int* dst = (const int*)d_in[2];
    float* out = (float*)d_out;

    const int E = in_sizes[1];                   // 2,000,000
    const int N = in_sizes[0] / DIM;             // 100,000
    const int NBK = (N + GNODES - 1) >> BSHIFT;  // 782
    const int nPart = (E + CE - 1) / CE;         // 245 partition chunks

    // workspace: cursor[MAXB]+spillCnt | offsets[N] | sliced f16 mirror | arena | spill
    char* w = (char*)d_ws;
    size_t curBytes = align256((size_t)(MAXB + 1) * sizeof(int));
    size_t offBytes = align256((size_t)N * sizeof(int));
    size_t xhBytes = align256((size_t)(N + 1) * DIM * 2);
    size_t fixedBytes = curBytes + offBytes + xhBytes;
    size_t spillReserve = 256 * 1024;

    size_t avail = (ws_size > fixedBytes + spillReserve)
                       ? (ws_size - fixedBytes - spillReserve) : 0;
    int cap = (int)((avail / sizeof(int)) / (size_t)NBK);
    if (cap > CAP_MAX) cap = CAP_MAX;
    if (cap < 64) cap = 64;    // degenerate ws; spill net keeps correctness

    int* cursor = (int*)w;                            // [NBK]
    int* spillCnt = cursor + MAXB;                    // [1]
    int* offsets = (int*)(w + curBytes);              // [N] local starts
    ushort* xh = (ushort*)(w + curBytes + offBytes);  // 8 x [(N+1)][16] f16
    int* arena = (int*)(w + fixedBytes);              // [NBK*cap]
    size_t arenaBytes = align256((size_t)NBK * cap * sizeof(int));
    int2* spill = (int2*)(w + fixedBytes + arenaBytes);
    int spillCap = (int)((ws_size > fixedBytes + arenaBytes)
                             ? (ws_size - fixedBytes - arenaBytes) / sizeof(int2)
                             : 0);

    // 1) zero cursors + spill counter
    (void)hipMemsetAsync(cursor, 0, (size_t)(MAXB + 1) * sizeof(int), stream);

    // 2) fused: partition (blocks 0..nPart) || sliced f16 convert (rest)
    {
        int grid = nPart + 1792;
        hipLaunchKernelGGL(hgnn_fused_prep, dim3(grid), dim3(256), 0, stream,
                           (const float4*)x, (ushort4*)xh, N,
                           src, dst, cursor, arena, cap,
                           spillCnt, spill, spillCap, E, NBK, nPart);
    }

    // 3) per-bucket counting sort -> node-grouped bare src ids + offsets
    hipLaunchKernelGGL(hgnn_refine, dim3(NBK), dim3(256), 0, stream,
                       arena, cap, cursor, offsets, N);

    // 4) dim-split aggregate: 8 dimgroups x NBK buckets, g = blockIdx&7
    hipLaunchKernelGGL(hgnn_aggregate_dsplit, dim3(NBK * 8), dim3(256), 0,
                       stream, x, (const uint2*)xh, arena, cap,
                       cursor, offsets, out, N);

    // 5) apply spilled edges (normally zero work)
    hipLaunchKernelGGL(hgnn_spill_apply, dim3(64), dim3(256), 0, stream,
                       (const float4*)x, spillCnt, spill, out, spillCap);
}

// Round 17
// 142.314 us; speedup vs baseline: 2.1947x; 2.1947x over previous
//
#include <hip/hip_runtime.h>
#include <hip/hip_fp16.h>

// HGNN aggregation: out = x + segment_sum(x[src_idx], dst_idx)
// x: [100000, 128] f32; src_idx/dst_idx: [2,000,000] int32.
//
// Round 17: revert to round-12 (proven best, 140.6 us).
//   - fused prep: partition into per-bucket arenas || f16 row-major mirror
//   - aggregate: 4 blocks/bucket, 32-bin LDS counting-sort of the quarter,
//     16 lanes x uint4 (16B) per row, 4 edges per load instr, f16 pk
//     accumulation, cross-quarter shfl reduce, exact f32 residual.
//   Aggregate is at its compulsory-fetch floor (263 MB @ ~2.9 TB/s):
//   dim-split alternatives (r13-r16) all regressed (LDS-atomic ceiling,
//   line-span, nt-latency). Do not re-attempt without a new mechanism.

constexpr int DIM = 128;
constexpr int BSHIFT = 7;            // 128 nodes per bucket
constexpr int GNODES = 1 << BSHIFT;  // 128
constexpr int MAXB = 1024;           // max buckets (N <= 131072)
constexpr int CE = 8192;             // edges per partition chunk
constexpr int CAP_MAX = 3072;        // arena slots per bucket
constexpr int QCAP = 1536;           // per-quarter sorted capacity (mean 640)

__global__ void hgnn_fused_prep(const float4* __restrict__ x4,
                                ushort4* __restrict__ xh4, int n4,
                                const int* __restrict__ src,
                                const int* __restrict__ dst,
                                int* __restrict__ cursor,
                                int* __restrict__ arena, int cap,
                                int* __restrict__ spillCnt,
                                int2* __restrict__ spill, int spillCap,
                                int nedges, int nbk, int nPart) {
    __shared__ int h[MAXB];
    __shared__ int lb[MAXB];
    const int tid = threadIdx.x;

    if ((int)blockIdx.x < nPart) {
        // ---- partition path ----
        int c0 = blockIdx.x * CE;
        int c1 = min(c0 + CE, nedges);
        for (int i = tid; i < nbk; i += blockDim.x) h[i] = 0;
        __syncthreads();
        for (int i = c0 + tid; i < c1; i += blockDim.x)
            atomicAdd(&h[dst[i] >> BSHIFT], 1);
        __syncthreads();
        for (int i = tid; i < nbk; i += blockDim.x)
            lb[i] = h[i] ? atomicAdd(&cursor[i], h[i]) : 0;
        __syncthreads();
        for (int i = c0 + tid; i < c1; i += blockDim.x) {
            int s = src[i];
            int d = dst[i];
            int bk = d >> BSHIFT;
            int pos = atomicAdd(&lb[bk], 1);
            if (pos < cap) {
                arena[(size_t)bk * cap + pos] = s | ((d & (GNODES - 1)) << 17);
            } else {
                int sp = atomicAdd(spillCnt, 1);
                if (sp < spillCap) spill[sp] = make_int2(s, d);
            }
        }
    } else {
        // ---- convert path (concurrent with partition) ----
        int bid = blockIdx.x - nPart;
        int nconv = gridDim.x - nPart;
        int i = bid * blockDim.x + tid;
        int stride = nconv * blockDim.x;
        for (int k = i; k < n4; k += stride) {
            float4 v = x4[k];
            ushort4 o;
            o.x = __half_as_ushort(__float2half_rn(v.x));
            o.y = __half_as_ushort(__float2half_rn(v.y));
            o.z = __half_as_ushort(__float2half_rn(v.z));
            o.w = __half_as_ushort(__float2half_rn(v.w));
            xh4[k] = o;
        }
        // zero pad row (row index N) for predicated gather
        if (bid == 0 && tid < 32) {
            ushort4 z; z.x = 0; z.y = 0; z.z = 0; z.w = 0;
            xh4[n4 + tid] = z;
        }
    }
}

// 4 blocks per bucket; block q sorts & aggregates quarter q (32 nodes).
__global__ void hgnn_aggregate(const float4* __restrict__ x4,
                               const uint4* __restrict__ xh16,
                               const int* __restrict__ arena, int cap,
                               const int* __restrict__ cursor,
                               float4* __restrict__ out4, int nnodes,
                               int* __restrict__ spillCnt,
                               int2* __restrict__ spill, int spillCap) {
    __shared__ int qsorted[QCAP];
    __shared__ int hoff[33];
    __shared__ int hcur[32];

    const int b = blockIdx.x >> 2;
    const int q = blockIdx.x & 3;
    const int tid = threadIdx.x;
    const int wv = tid >> 6;
    const int lane = tid & 63;
    const int qg = lane >> 4;     // quarter group 0..3 (edge selector)
    const int cl = lane & 15;     // 16 lanes x 16B = one 256B f16 row
    const int ZROW = nnodes;      // zeroed pad row in f16 mirror

    int cnt = cursor[b];
    if (cnt > cap) cnt = cap;
    const int* ar = arena + (size_t)b * cap;

    // pass 1: 32-bin histogram of this quarter's edges
    if (tid < 32) hcur[tid] = 0;
    __syncthreads();
    for (int i = tid; i < cnt; i += blockDim.x) {
        int dl = ar[i] >> 17;
        if ((dl >> 5) == q) atomicAdd(&hcur[dl & 31], 1);
    }
    __syncthreads();

    // inclusive scan -> hoff[1..32], hoff[0] = 0
    int myc = (tid < 32) ? hcur[tid] : 0;
    if (tid < 32) hoff[tid + 1] = myc;
    if (tid == 0) hoff[0] = 0;
    __syncthreads();
    for (int off = 1; off < 32; off <<= 1) {
        int v = (tid < 32 && tid >= off) ? hoff[tid + 1 - off] : 0;
        __syncthreads();
        if (tid < 32) hoff[tid + 1] += v;
        __syncthreads();
    }
    if (tid < 32) hcur[tid] = hoff[tid];
    __syncthreads();

    // pass 2: scatter into sorted LDS list
    for (int i = tid; i < cnt; i += blockDim.x) {
        int p = ar[i];
        int dl = p >> 17;
        if ((dl >> 5) == q) {
            int pos = atomicAdd(&hcur[dl & 31], 1);
            if (pos < QCAP) {
                qsorted[pos] = p;
            } else {                       // pathological skew only
                int sp = atomicAdd(spillCnt, 1);
                if (sp < spillCap)
                    spill[sp] = make_int2(p & 0x1FFFF, (b << BSHIFT) + dl);
            }
        }
    }
    __syncthreads();

    // gather: wave wv handles 8 nodes in pairs; 4 edges per load instr
    const int nodeBase = (b << BSHIFT) + q * 32 + wv * 8;
    const __half2 hz = __floats2half2_rn(0.f, 0.f);
    for (int r = 0; r < 8; r += 2) {
        int n0 = nodeBase + r;
        if (n0 >= nnodes) break;
        int n1 = n0 + 1;
        bool has1 = n1 < nnodes;

        int bin0 = wv * 8 + r;
        int s0 = hoff[bin0];
        int e0 = hoff[bin0 + 1];
        int s1 = hoff[bin0 + 1];
        int e1 = hoff[bin0 + 2];
        if (s0 > QCAP) s0 = QCAP;
        if (e0 > QCAP) e0 = QCAP;
        if (s1 > QCAP) s1 = QCAP;
        if (e1 > QCAP) e1 = QCAP;
        int m0 = e0 - s0;
        int m1 = has1 ? (e1 - s1) : 0;
        int mm = max(m0, m1);

        // two f16 accumulator chains per node
        __half2 a0[4] = {hz, hz, hz, hz}, b0[4] = {hz, hz, hz, hz};
        __half2 a1[4] = {hz, hz, hz, hz}, b1[4] = {hz, hz, hz, hz};

        for (int j = 0; j < mm; j += 16) {
#pragma unroll
            for (int kk = 0; kk < 4; ++kk) {          // n0: 16 edges
                int e = j + 4 * kk + qg;
                int p = (e < m0) ? (qsorted[s0 + e] & 0x1FFFF) : ZROW;
                uint4 v = xh16[(size_t)p * 16 + cl];
                __half2 h0 = *reinterpret_cast<const __half2*>(&v.x);
                __half2 h1 = *reinterpret_cast<const __half2*>(&v.y);
                __half2 h2 = *reinterpret_cast<const __half2*>(&v.z);
                __half2 h3 = *reinterpret_cast<const __half2*>(&v.w);
                if (kk & 1) {
                    b0[0] = __hadd2(b0[0], h0); b0[1] = __hadd2(b0[1], h1);
                    b0[2] = __hadd2(b0[2], h2); b0[3] = __hadd2(b0[3], h3);
                } else {
                    a0[0] = __hadd2(a0[0], h0); a0[1] = __hadd2(a0[1], h1);
                    a0[2] = __hadd2(a0[2], h2); a0[3] = __hadd2(a0[3], h3);
                }
            }
#pragma unroll
            for (int kk = 0; kk < 4; ++kk) {          // n1: 16 edges
                int e = j + 4 * kk + qg;
                int p = (e < m1) ? (qsorted[s1 + e] & 0x1FFFF) : ZROW;
                uint4 v = xh16[(size_t)p * 16 + cl];
                __half2 h0 = *reinterpret_cast<const __half2*>(&v.x);
                __half2 h1 = *reinterpret_cast<const __half2*>(&v.y);
                __half2 h2 = *reinterpret_cast<const __half2*>(&v.z);
                __half2 h3 = *reinterpret_cast<const __half2*>(&v.w);
                if (kk & 1) {
                    b1[0] = __hadd2(b1[0], h0); b1[1] = __hadd2(b1[1], h1);
                    b1[2] = __hadd2(b1[2], h2); b1[3] = __hadd2(b1[3], h3);
                } else {
                    a1[0] = __hadd2(a1[0], h0); a1[1] = __hadd2(a1[1], h1);
                    a1[2] = __hadd2(a1[2], h2); a1[3] = __hadd2(a1[3], h3);
                }
            }
        }

        // finish node n0: cross-quarter reduce (lanes ^16, ^32), f32 + residual
        {
            float f[8];
#pragma unroll
            for (int t = 0; t < 4; ++t) {
                __half2 s = __hadd2(a0[t], b0[t]);
                int si = *reinterpret_cast<int*>(&s);
                int sx = __shfl_xor(si, 16);
                s = __hadd2(s, *reinterpret_cast<__half2*>(&sx));
                si = *reinterpret_cast<int*>(&s);
                sx = __shfl_xor(si, 32);
                s = __hadd2(s, *reinterpret_cast<__half2*>(&sx));
                float2 fv = __half22float2(s);
                f[2 * t] = fv.x;
                f[2 * t + 1] = fv.y;
            }
            if (qg == 0) {
                float4 xa = x4[(size_t)n0 * 32 + 2 * cl];
                float4 xb = x4[(size_t)n0 * 32 + 2 * cl + 1];
                out4[(size_t)n0 * 32 + 2 * cl] =
                    make_float4(xa.x + f[0], xa.y + f[1], xa.z + f[2], xa.w + f[3]);
                out4[(size_t)n0 * 32 + 2 * cl + 1] =
                    make_float4(xb.x + f[4], xb.y + f[5], xb.z + f[6], xb.w + f[7]);
            }
        }
        // finish node n1
        if (has1) {
            float f[8];
#pragma unroll
            for (int t = 0; t < 4; ++t) {
                __half2 s = __hadd2(a1[t], b1[t]);
                int si = *reinterpret_cast<int*>(&s);
                int sx = __shfl_xor(si, 16);
                s = __hadd2(s, *reinterpret_cast<__half2*>(&sx));
                si = *reinterpret_cast<int*>(&s);
                sx = __shfl_xor(si, 32);
                s = __hadd2(s, *reinterpret_cast<__half2*>(&sx));
                float2 fv = __half22float2(s);
                f[2 * t] = fv.x;
                f[2 * t + 1] = fv.y;
            }
            if (qg == 0) {
                float4 xa = x4[(size_t)n1 * 32 + 2 * cl];
                float4 xb = x4[(size_t)n1 * 32 + 2 * cl + 1];
                out4[(size_t)n1 * 32 + 2 * cl] =
                    make_float4(xa.x + f[0], xa.y + f[1], xa.z + f[2], xa.w + f[3]);
                out4[(size_t)n1 * 32 + 2 * cl + 1] =
                    make_float4(xb.x + f[4], xb.y + f[5], xb.z + f[6], xb.w + f[7]);
            }
        }
    }
}

// handles overflow edges (expected none on this data); exact f32 path
__global__ void hgnn_spill_apply(const float4* __restrict__ x4,
                                 const int* __restrict__ spillCnt,
                                 const int2* __restrict__ spill,
                                 float* __restrict__ out, int spillCap) {
    int n = *spillCnt;
    if (n > spillCap) n = spillCap;
    int i = blockIdx.x * blockDim.x + threadIdx.x;
    int stride = gridDim.x * blockDim.x;
    for (int k = i; k < n * 32; k += stride) {
        int e = k >> 5;
        int cc = k & 31;
        int2 sd = spill[e];
        float4 v = x4[(size_t)sd.x * 32 + cc];
        float* o = out + (size_t)sd.y * DIM + cc * 4;
        atomicAdd(o + 0, v.x);
        atomicAdd(o + 1, v.y);
        atomicAdd(o + 2, v.z);
        atomicAdd(o + 3, v.w);
    }
}

static inline size_t align256(size_t v) { return (v + 255) & ~(size_t)255; }

extern "C" void kernel_launch(void* const* d_in, const int* in_sizes, int n_in,
                              void* d_out, int out_size, void* d_ws, size_t ws_size,
                              hipStream_t stream) {
    const float* x = (const float*)d_in[0];
    const int* src = (const int*)d_in[1];
    const int* dst = (const int*)d_in[2];
    float* out = (float*)d_out;

    const int E = in_sizes[1];                   // 2,000,000
    const int N = in_sizes[0] / DIM;             // 100,000
    const int n4 = N * (DIM / 4);                // 3.2M float4 (= ushort4 mirror elems)
    const int NBK = (N + GNODES - 1) >> BSHIFT;  // 782
    const int nPart = (E + CE - 1) / CE;         // 245 partition chunks

    // workspace: cursor[MAXB] + spillCnt | f16 mirror (N+1 rows) | arena | spill
    char* w = (char*)d_ws;
    size_t curBytes = align256((size_t)(MAXB + 1) * sizeof(int));
    size_t xhBytes = align256((size_t)(N + 1) * DIM * 2);   // +pad row
    size_t fixedBytes = curBytes + xhBytes;
    size_t spillReserve = 256 * 1024;

    size_t avail = (ws_size > fixedBytes + spillReserve)
                       ? (ws_size - fixedBytes - spillReserve) : 0;
    int cap = (int)((avail / sizeof(int)) / (size_t)NBK);
    if (cap > CAP_MAX) cap = CAP_MAX;
    if (cap < 64) cap = 64;    // degenerate ws; spill net keeps correctness

    int* cursor = (int*)w;                        // [NBK]
    int* spillCnt = cursor + MAXB;                // [1]
    ushort* xh = (ushort*)(w + curBytes);         // [(N+1)*128] f16
    int* arena = (int*)(w + fixedBytes);          // [NBK*cap]
    size_t arenaBytes = align256((size_t)NBK * cap * sizeof(int));
    int2* spill = (int2*)(w + fixedBytes + arenaBytes);
    int spillCap = (int)((ws_size > fixedBytes + arenaBytes)
                             ? (ws_size - fixedBytes - arenaBytes) / sizeof(int2)
                             : 0);

    // 1) zero cursors + counters
    (void)hipMemsetAsync(cursor, 0, (size_t)(MAXB + 1) * sizeof(int), stream);

    // 2) static fused: partition (blocks 0..nPart) || f16 convert (rest)
    {
        int grid = nPart + 1792;
        hipLaunchKernelGGL(hgnn_fused_prep, dim3(grid), dim3(256), 0, stream,
                           (const float4*)x, (ushort4*)xh, n4,
                           src, dst, cursor, arena, cap,
                           spillCnt, spill, spillCap, E, NBK, nPart);
    }

    // 3) quarter-sort + 16B-lane gather-aggregate (4 blocks per bucket)
    hipLaunchKernelGGL(hgnn_aggregate, dim3(NBK * 4), dim3(256), 0, stream,
                       (const float4*)x, (const uint4*)xh, arena, cap,
                       cursor, (float4*)out, N, spillCnt, spill, spillCap);

    // 4) apply spilled edges (normally zero work)
    hipLaunchKernelGGL(hgnn_spill_apply, dim3(64), dim3(256), 0, stream,
                       (const float4*)x, spillCnt, spill, out, spillCap);
}